// Round 1
// baseline (417.391 us; speedup 1.0000x reference)
//
#include <hip/hip_runtime.h>
#include <hip/hip_fp16.h>

#define NQ     50000
#define MS     50000
#define NH     32
#define NK     15
#define CIN    64
#define COUT   128
#define QT     16
#define INV_EXT (1.0f/0.06f)

typedef unsigned int   uint32;

// Fused KPConv: per block of QT=16 queries
//  Phase A: h[q][j][k] = max(1 - |s[ind]-q - kp[k]| / ext, 0)  -> LDS fp16
//  Phase B: fpk[q][k][c] = sum_j h * x[ind[j]][c]              -> LDS bf16
//  Phase C: out[q][o] = sum_{k,c} fpk * W[k][c][o]             (W streamed, coalesced)
// LDS: 16KB (h) + 30KB (fpk) + 1KB (inds) = 47KB -> 3 blocks/CU.
__global__ __launch_bounds__(256, 3)
void kpconv_fused(const float* __restrict__ q_pts,
                  const float* __restrict__ s_pts,
                  const float* __restrict__ x,
                  const float* __restrict__ w,
                  const float* __restrict__ kp,
                  const int*   __restrict__ nind,
                  float* __restrict__ out)
{
    __shared__ __half        h_lds[QT][NH][16];     // 16384 B (k padded to 16, [15]=0)
    __shared__ unsigned short fpk_lds[QT][NK*CIN];  // 30720 B (bf16 bits)
    __shared__ unsigned short ind_lds[QT][NH];      // 1024 B

    const int t  = threadIdx.x;
    const int q0 = blockIdx.x * QT;

    // ---------------- Phase A: influence weights ----------------
    // kernel points: uniform -> scalar loads/SGPRs
    float kx[NK], ky[NK], kz[NK];
    #pragma unroll
    for (int k = 0; k < NK; ++k) {
        kx[k] = kp[k*3+0]; ky[k] = kp[k*3+1]; kz[k] = kp[k*3+2];
    }

    #pragma unroll
    for (int p = t; p < QT*NH; p += 256) {
        const int q = p >> 5;
        const int j = p & 31;
        const int ind = nind[(q0 + q)*NH + j];
        const int ic  = (ind < MS) ? ind : (MS - 1);
        ind_lds[q][j] = (unsigned short)ic;
        float sx, sy, sz;
        if (ind < MS) {
            sx = s_pts[ind*3+0]; sy = s_pts[ind*3+1]; sz = s_pts[ind*3+2];
        } else {
            sx = 1e6f; sy = 1e6f; sz = 1e6f;   // shadow point -> h = 0
        }
        const float qx = q_pts[(q0+q)*3+0];
        const float qy = q_pts[(q0+q)*3+1];
        const float qz = q_pts[(q0+q)*3+2];
        const float nx = sx - qx, ny = sy - qy, nz = sz - qz;
        #pragma unroll
        for (int k = 0; k < NK; ++k) {
            const float dx = nx - kx[k], dy = ny - ky[k], dz = nz - kz[k];
            const float sq = dx*dx + dy*dy + dz*dz;
            float hh = 1.0f - sqrtf(sq) * INV_EXT;
            hh = (hh > 0.0f) ? hh : 0.0f;
            h_lds[q][j][k] = (__half)hh;
        }
        h_lds[q][j][15] = (__half)0.0f;
    }
    __syncthreads();

    // ---------------- Phase B: fpk = h . x_gathered ----------------
    {
        const int c  = t & 63;       // channel lane (wave = one qg, coalesced row reads)
        const int qg = t >> 6;       // 0..3
        #pragma unroll
        for (int qt = 0; qt < QT/4; ++qt) {
            const int q = qg*4 + qt;
            float acc[16];
            #pragma unroll
            for (int k = 0; k < 16; ++k) acc[k] = 0.0f;
            #pragma unroll 4
            for (int j = 0; j < NH; ++j) {
                const float xv = x[(int)ind_lds[q][j]*CIN + c];  // coalesced 256B row
                const float4* hp4 = (const float4*)&h_lds[q][j][0];
                float4 ha = hp4[0];   // halves 0..7  (one ds_read_b128, broadcast)
                float4 hb = hp4[1];   // halves 8..15
                const __half2* h2a = reinterpret_cast<const __half2*>(&ha);
                const __half2* h2b = reinterpret_cast<const __half2*>(&hb);
                #pragma unroll
                for (int k2 = 0; k2 < 4; ++k2) {
                    acc[k2*2+0] += __low2float (h2a[k2]) * xv;
                    acc[k2*2+1] += __high2float(h2a[k2]) * xv;
                    acc[8+k2*2+0] += __low2float (h2b[k2]) * xv;
                    acc[8+k2*2+1] += __high2float(h2b[k2]) * xv;
                }
            }
            #pragma unroll
            for (int k = 0; k < NK; ++k) {
                uint32 b = __float_as_uint(acc[k]);
                b += 0x7fffu + ((b >> 16) & 1u);       // round-to-nearest-even bf16
                fpk_lds[q][k*CIN + c] = (unsigned short)(b >> 16);
            }
        }
    }
    __syncthreads();

    // ---------------- Phase C: out = fpk . W ----------------
    {
        const int o4 = (t & 31) * 4;   // 32 lanes cover o = 0..127 via float4
        const int q2 = t >> 5;         // 0..7 -> query pair
        const int qa = q2*2, qb = qa + 1;
        float a0=0,a1=0,a2=0,a3=0;
        float b0=0,b1=0,b2=0,b3=0;
        const unsigned short* fa = &fpk_lds[qa][0];
        const unsigned short* fb = &fpk_lds[qb][0];
        // (k,c) flattened: both fpk and W are contiguous in kc = k*64+c
        #pragma unroll 4
        for (int kc = 0; kc < NK*CIN; kc += 2) {
            const float4 w0 = *(const float4*)&w[(kc+0)*COUT + o4];
            const float4 w1 = *(const float4*)&w[(kc+1)*COUT + o4];
            const uint32 ua = *(const uint32*)&fa[kc];
            const uint32 ub = *(const uint32*)&fb[kc];
            const float fa0 = __uint_as_float(ua << 16);
            const float fa1 = __uint_as_float(ua & 0xffff0000u);
            const float fb0 = __uint_as_float(ub << 16);
            const float fb1 = __uint_as_float(ub & 0xffff0000u);
            a0 += fa0*w0.x; a1 += fa0*w0.y; a2 += fa0*w0.z; a3 += fa0*w0.w;
            b0 += fb0*w0.x; b1 += fb0*w0.y; b2 += fb0*w0.z; b3 += fb0*w0.w;
            a0 += fa1*w1.x; a1 += fa1*w1.y; a2 += fa1*w1.z; a3 += fa1*w1.w;
            b0 += fb1*w1.x; b1 += fb1*w1.y; b2 += fb1*w1.z; b3 += fb1*w1.w;
        }
        *(float4*)&out[(q0+qa)*COUT + o4] = make_float4(a0,a1,a2,a3);
        *(float4*)&out[(q0+qb)*COUT + o4] = make_float4(b0,b1,b2,b3);
    }
}

extern "C" void kernel_launch(void* const* d_in, const int* in_sizes, int n_in,
                              void* d_out, int out_size, void* d_ws, size_t ws_size,
                              hipStream_t stream) {
    const float* q_pts = (const float*)d_in[0];
    const float* s_pts = (const float*)d_in[1];
    const float* x     = (const float*)d_in[2];
    const float* wts   = (const float*)d_in[3];
    const float* kp    = (const float*)d_in[4];
    const int*   nind  = (const int*)d_in[5];
    float* out = (float*)d_out;

    dim3 grid(NQ / QT);   // 3125 blocks, N divisible by 16
    dim3 block(256);
    hipLaunchKernelGGL(kpconv_fused, grid, block, 0, stream,
                       q_pts, s_pts, x, wts, kp, nind, out);
}

// Round 2
// 185.452 us; speedup vs baseline: 2.2507x; 2.2507x over previous
//
#include <hip/hip_runtime.h>

#define NQ     50000
#define MS     50000
#define NH     32
#define NK     15
#define CIN    64
#define COUT   128
#define QT     16
#define KC     (NK*CIN)          // 960
#define FPK_STRIDE 968           // 960 + 8 pad: 484 dwords, %32==4 -> 2-way (free)
#define INV_EXT (1.0f/0.06f)

typedef unsigned int uint32;
typedef __bf16 bf16x8 __attribute__((ext_vector_type(8)));
typedef float  f32x4  __attribute__((ext_vector_type(4)));

__device__ __forceinline__ unsigned short f32_to_bf16_rne(float f) {
    uint32 b = __float_as_uint(f);
    b += 0x7fffu + ((b >> 16) & 1u);
    return (unsigned short)(b >> 16);
}

// ---- W [960][128] fp32  ->  Wt [128][960] bf16 (in d_ws), LDS-tiled transpose ----
__global__ __launch_bounds__(256)
void wt_convert(const float* __restrict__ w, unsigned short* __restrict__ wt) {
    __shared__ unsigned short st[8 * 128];   // 8 k-rows x 128 n
    const int k0 = blockIdx.x * 8;           // 120 blocks
    const int t  = threadIdx.x;
    // coalesced read: 8 rows x 128 cols = 1024 floats, float4 per thread
    {
        const int flat = t * 4;              // 0..1023
        const int k = flat >> 7;
        const int n = flat & 127;
        const float4 v = *(const float4*)&w[(k0 + k) * COUT + n];
        st[k*128 + n + 0] = f32_to_bf16_rne(v.x);
        st[k*128 + n + 1] = f32_to_bf16_rne(v.y);
        st[k*128 + n + 2] = f32_to_bf16_rne(v.z);
        st[k*128 + n + 3] = f32_to_bf16_rne(v.w);
    }
    __syncthreads();
    // transposed write: each thread writes 4 consecutive k's of one n
    {
        const int n    = t >> 1;
        const int half = (t & 1) * 4;
        ushort4 o;
        o.x = st[(half + 0)*128 + n];
        o.y = st[(half + 1)*128 + n];
        o.z = st[(half + 2)*128 + n];
        o.w = st[(half + 3)*128 + n];
        *(ushort4*)&wt[n * KC + k0 + half] = o;
    }
}

// ---- fused KPConv ----
// Phase A: h[q][j][k] fp32 -> LDS (broadcast-friendly)
// Phase B: fpk[q][kc] = sum_j h * x_gather  (VALU fp32, bf16 pack -> LDS)
// Phase C: out[16q x 128o] = fpk[16 x 960] . Wt^T   via mfma_f32_16x16x32_bf16
__global__ __launch_bounds__(256, 2)
void kpconv_fused(const float* __restrict__ q_pts,
                  const float* __restrict__ s_pts,
                  const float* __restrict__ x,
                  const unsigned short* __restrict__ wt,
                  const float* __restrict__ kp,
                  const int*   __restrict__ nind,
                  float* __restrict__ out)
{
    __shared__ float          h_lds[QT][NH][16];       // 32768 B (k padded to 16)
    __shared__ unsigned short fpk_lds[QT][FPK_STRIDE]; // 30976 B (bf16 bits)
    __shared__ unsigned short ind_lds[QT][NH];         // 1024 B

    const int t  = threadIdx.x;
    const int q0 = blockIdx.x * QT;

    // ---------------- Phase A ----------------
    float kx[NK], ky[NK], kz[NK];
    #pragma unroll
    for (int k = 0; k < NK; ++k) {
        kx[k] = kp[k*3+0]; ky[k] = kp[k*3+1]; kz[k] = kp[k*3+2];
    }

    #pragma unroll
    for (int p = t; p < QT*NH; p += 256) {
        const int q = p >> 5;
        const int j = p & 31;
        const int ind = nind[(q0 + q)*NH + j];
        const int ic  = (ind < MS) ? ind : (MS - 1);
        ind_lds[q][j] = (unsigned short)ic;
        float sx, sy, sz;
        if (ind < MS) {
            sx = s_pts[ind*3+0]; sy = s_pts[ind*3+1]; sz = s_pts[ind*3+2];
        } else {
            sx = 1e6f; sy = 1e6f; sz = 1e6f;   // shadow -> h = 0
        }
        const float nx = sx - q_pts[(q0+q)*3+0];
        const float ny = sy - q_pts[(q0+q)*3+1];
        const float nz = sz - q_pts[(q0+q)*3+2];
        #pragma unroll
        for (int k = 0; k < NK; ++k) {
            const float dx = nx - kx[k], dy = ny - ky[k], dz = nz - kz[k];
            float hh = 1.0f - sqrtf(dx*dx + dy*dy + dz*dz) * INV_EXT;
            h_lds[q][j][k] = (hh > 0.0f) ? hh : 0.0f;
        }
        h_lds[q][j][15] = 0.0f;
    }
    __syncthreads();

    // ---------------- Phase B ----------------
    {
        const int c  = t & 63;       // channel lane -> coalesced 256B x-row reads
        const int qg = t >> 6;       // wave id; whole wave shares q -> h reads broadcast
        #pragma unroll
        for (int qt = 0; qt < QT/4; ++qt) {
            const int q = qg*4 + qt;
            float acc[16];
            #pragma unroll
            for (int k = 0; k < 16; ++k) acc[k] = 0.0f;
            #pragma unroll 8
            for (int j = 0; j < NH; ++j) {
                const float xv = x[(int)ind_lds[q][j]*CIN + c];
                const float4* hp = (const float4*)&h_lds[q][j][0];
                const float4 h0 = hp[0], h1 = hp[1], h2 = hp[2], h3 = hp[3];
                acc[0]  += h0.x*xv; acc[1]  += h0.y*xv; acc[2]  += h0.z*xv; acc[3]  += h0.w*xv;
                acc[4]  += h1.x*xv; acc[5]  += h1.y*xv; acc[6]  += h1.z*xv; acc[7]  += h1.w*xv;
                acc[8]  += h2.x*xv; acc[9]  += h2.y*xv; acc[10] += h2.z*xv; acc[11] += h2.w*xv;
                acc[12] += h3.x*xv; acc[13] += h3.y*xv; acc[14] += h3.z*xv;
            }
            #pragma unroll
            for (int k = 0; k < NK; ++k)
                fpk_lds[q][k*CIN + c] = f32_to_bf16_rne(acc[k]);
        }
    }
    __syncthreads();

    // ---------------- Phase C: MFMA ----------------
    {
        const int l   = t & 63;
        const int w   = t >> 6;          // wave 0..3 -> n-tiles {w*32, w*32+16}
        const int n0  = w * 32;
        const int col = l & 15;
        const int kg  = l >> 4;          // 0..3
        f32x4 acc0 = {0.f,0.f,0.f,0.f};
        f32x4 acc1 = {0.f,0.f,0.f,0.f};
        const unsigned short* arow = &fpk_lds[0][0] + col * FPK_STRIDE + kg * 8; // A row = query
        const unsigned short* b0p  = wt + (n0 + col) * KC + kg * 8;
        const unsigned short* b1p  = b0p + 16 * KC;
        #pragma unroll 6
        for (int ks = 0; ks < KC/32; ++ks) {          // 30 k-steps
            const bf16x8 a  = *(const bf16x8*)(arow + ks*32);
            const bf16x8 b0 = *(const bf16x8*)(b0p  + ks*32);
            const bf16x8 b1 = *(const bf16x8*)(b1p  + ks*32);
            acc0 = __builtin_amdgcn_mfma_f32_16x16x32_bf16(a, b0, acc0, 0, 0, 0);
            acc1 = __builtin_amdgcn_mfma_f32_16x16x32_bf16(a, b1, acc1, 0, 0, 0);
        }
        const int rbase = kg * 4;        // C/D: row=(lane>>4)*4+reg, col=lane&15
        #pragma unroll
        for (int r = 0; r < 4; ++r) {
            out[(q0 + rbase + r)*COUT + n0 + col]      = acc0[r];
            out[(q0 + rbase + r)*COUT + n0 + 16 + col] = acc1[r];
        }
    }
}

extern "C" void kernel_launch(void* const* d_in, const int* in_sizes, int n_in,
                              void* d_out, int out_size, void* d_ws, size_t ws_size,
                              hipStream_t stream) {
    const float* q_pts = (const float*)d_in[0];
    const float* s_pts = (const float*)d_in[1];
    const float* x     = (const float*)d_in[2];
    const float* wts   = (const float*)d_in[3];
    const float* kp    = (const float*)d_in[4];
    const int*   nind  = (const int*)d_in[5];
    float* out = (float*)d_out;
    unsigned short* wt = (unsigned short*)d_ws;   // 245,760 B needed

    hipLaunchKernelGGL(wt_convert, dim3(KC/8), dim3(256), 0, stream, wts, wt);
    hipLaunchKernelGGL(kpconv_fused, dim3(NQ/QT), dim3(256), 0, stream,
                       q_pts, s_pts, x, wt, kp, nind, out);
}

// Round 3
// 172.533 us; speedup vs baseline: 2.4192x; 1.0749x over previous
//
#include <hip/hip_runtime.h>

#define NQ     50000
#define MS     50000
#define NH     32
#define NK     15
#define CIN    64
#define COUT   128
#define QT     16
#define KC     (NK*CIN)          // 960
#define INV_EXT (1.0f/0.06f)

typedef unsigned int   uint32;
typedef unsigned short u16;
typedef _Float16 f16;
typedef _Float16 f16x2 __attribute__((ext_vector_type(2)));
typedef _Float16 f16x4 __attribute__((ext_vector_type(4)));
typedef _Float16 f16x8 __attribute__((ext_vector_type(8)));
typedef float    f32x4 __attribute__((ext_vector_type(4)));

// ws layout: [0, WB_BYTES): WB fp16 fragment-packed W; then xh (x as fp16) if room
#define WB_ELEMS (8*30*64*8)     // 122880
#define WB_BYTES (WB_ELEMS*2)    // 245760
#define XH_BYTES (MS*CIN*2)      // 6,400,000

__device__ __forceinline__ float dot2_f16(f16x2 a, f16x2 b, float c) {
#if __has_builtin(__builtin_amdgcn_fdot2)
    return __builtin_amdgcn_fdot2(a, b, c, false);
#else
    return c + (float)a[0]*(float)b[0] + (float)a[1]*(float)b[1];
#endif
}

// ---- x f32 -> fp16 (exact grid: 3125*256*4 = 3,200,000) ----
__global__ __launch_bounds__(256)
void xh_pack(const float* __restrict__ x, f16* __restrict__ xh) {
    const int i = (blockIdx.x * 256 + threadIdx.x) * 4;
    const float4 v = *(const float4*)&x[i];
    f16x4 o; o[0]=(f16)v.x; o[1]=(f16)v.y; o[2]=(f16)v.z; o[3]=(f16)v.w;
    *(f16x4*)&xh[i] = o;
}

// ---- W [960][128] f32 -> WB fp16 in MFMA B-fragment order ----
// WB[nt][ks][lane][e]: lane = kg*16+col holds W[ks*32+kg*8+e][nt*16+col]
__global__ __launch_bounds__(64)
void wb_pack(const float* __restrict__ w, f16* __restrict__ wb) {
    const int nt = blockIdx.x / 30;
    const int ks = blockIdx.x % 30;
    const int l  = threadIdx.x;
    const int col = l & 15, kg = l >> 4;
    f16x8 frag;
    #pragma unroll
    for (int e = 0; e < 8; ++e)
        frag[e] = (f16)w[(ks*32 + kg*8 + e)*COUT + nt*16 + col];
    *(f16x8*)&wb[((nt*30 + ks)*64 + l)*8] = frag;
}

// ---- fused KPConv ----
__global__ __launch_bounds__(256, 3)
void kpconv_fused(const float* __restrict__ q_pts,
                  const float* __restrict__ s_pts,
                  const float* __restrict__ x,
                  const f16*  __restrict__ xh,
                  const f16*  __restrict__ wb,
                  const float* __restrict__ kp,
                  const int*   __restrict__ nind,
                  float* __restrict__ out,
                  int use_xh)
{
    __shared__ u16    fpkA[QT*KC];     // 30720 B, fp16 bits, XOR-swizzled; head reused as nb[]
    __shared__ uint32 h2[QT*260];      // 16640 B: per q 260 u32; [q*260+jp*16+k] = fp16 pair (h[2jp][k],h[2jp+1][k])
    __shared__ u16    inds[QT*NH];     // 1024 B

    float* nb = (float*)fpkA;          // nb[q*100 + j*3 + d], 6400 B (stride 100 dwords: q's spread banks)

    const int t  = threadIdx.x;
    const int q0 = blockIdx.x * QT;

    // ---------------- stage neighbors (centered coords) ----------------
    #pragma unroll
    for (int p = t; p < QT*NH; p += 256) {
        const int q = p >> 5, j = p & 31;
        const int ind = nind[(q0 + q)*NH + j];
        const bool valid = (ind < MS);
        inds[p] = (u16)(valid ? ind : 0);
        float sx, sy, sz;
        if (valid) { sx = s_pts[ind*3+0]; sy = s_pts[ind*3+1]; sz = s_pts[ind*3+2]; }
        else       { sx = 1e6f; sy = 1e6f; sz = 1e6f; }    // shadow -> h = 0
        nb[q*100 + j*3 + 0] = sx - q_pts[(q0+q)*3+0];
        nb[q*100 + j*3 + 1] = sy - q_pts[(q0+q)*3+1];
        nb[q*100 + j*3 + 2] = sz - q_pts[(q0+q)*3+2];
    }
    __syncthreads();

    // ---------------- Phase A: h2 pairs (thread = (q,k)) ----------------
    {
        const int q = t >> 4, k = t & 15;
        if (k < NK) {
            const float kx = kp[k*3+0], ky = kp[k*3+1], kz = kp[k*3+2];
            const float* nbq = &nb[q*100];
            uint32* hrow = &h2[q*260];
            #pragma unroll
            for (int jp = 0; jp < 16; ++jp) {
                float dx0 = nbq[jp*6+0]-kx, dy0 = nbq[jp*6+1]-ky, dz0 = nbq[jp*6+2]-kz;
                float dx1 = nbq[jp*6+3]-kx, dy1 = nbq[jp*6+4]-ky, dz1 = nbq[jp*6+5]-kz;
                float h0 = 1.0f - sqrtf(dx0*dx0+dy0*dy0+dz0*dz0)*INV_EXT;
                float h1 = 1.0f - sqrtf(dx1*dx1+dy1*dy1+dz1*dz1)*INV_EXT;
                h0 = (h0 > 0.0f) ? h0 : 0.0f;
                h1 = (h1 > 0.0f) ? h1 : 0.0f;
                f16x2 p2; p2[0] = (f16)h0; p2[1] = (f16)h1;
                hrow[jp*16 + k] = __builtin_bit_cast(uint32, p2);
            }
        }
    }
    __syncthreads();   // h2 ready; nb region may now be overwritten (fpkA)

    // ---------------- Phase B: fpk[q][k][c] via v_dot2 over j-pairs ----------------
    {
        const int c  = t & 63;
        const int qg = t >> 6;
        #pragma unroll
        for (int qt2 = 0; qt2 < 4; ++qt2) {
            const int q = qg*4 + qt2;
            // gather this channel's 32 neighbor features (fp16 bits)
            uint32 xv[NH];
            if (use_xh) {
                #pragma unroll 8
                for (int j = 0; j < NH; ++j)
                    xv[j] = (uint32)*(const u16*)&xh[(int)inds[q*NH+j]*CIN + c];
            } else {
                #pragma unroll 8
                for (int j = 0; j < NH; ++j) {
                    const f16 hv = (f16)x[(int)inds[q*NH+j]*CIN + c];
                    xv[j] = (uint32)__builtin_bit_cast(u16, hv);
                }
            }
            f16x2 xp[16];
            #pragma unroll
            for (int jp = 0; jp < 16; ++jp)
                xp[jp] = __builtin_bit_cast(f16x2, xv[2*jp] | (xv[2*jp+1] << 16));

            float acc[NK];
            #pragma unroll
            for (int k = 0; k < NK; ++k) acc[k] = 0.0f;

            const uint32* hrow = &h2[q*260];
            #pragma unroll
            for (int jp = 0; jp < 16; ++jp) {
                const uint4 ha = *(const uint4*)&hrow[jp*16 + 0];   // k 0..3   (broadcast)
                const uint4 hb = *(const uint4*)&hrow[jp*16 + 4];   // k 4..7
                const uint4 hc = *(const uint4*)&hrow[jp*16 + 8];   // k 8..11
                const uint4 hd = *(const uint4*)&hrow[jp*16 + 12];  // k 12..14
                const f16x2 b = xp[jp];
                acc[0]  = dot2_f16(__builtin_bit_cast(f16x2, ha.x), b, acc[0]);
                acc[1]  = dot2_f16(__builtin_bit_cast(f16x2, ha.y), b, acc[1]);
                acc[2]  = dot2_f16(__builtin_bit_cast(f16x2, ha.z), b, acc[2]);
                acc[3]  = dot2_f16(__builtin_bit_cast(f16x2, ha.w), b, acc[3]);
                acc[4]  = dot2_f16(__builtin_bit_cast(f16x2, hb.x), b, acc[4]);
                acc[5]  = dot2_f16(__builtin_bit_cast(f16x2, hb.y), b, acc[5]);
                acc[6]  = dot2_f16(__builtin_bit_cast(f16x2, hb.z), b, acc[6]);
                acc[7]  = dot2_f16(__builtin_bit_cast(f16x2, hb.w), b, acc[7]);
                acc[8]  = dot2_f16(__builtin_bit_cast(f16x2, hc.x), b, acc[8]);
                acc[9]  = dot2_f16(__builtin_bit_cast(f16x2, hc.y), b, acc[9]);
                acc[10] = dot2_f16(__builtin_bit_cast(f16x2, hc.z), b, acc[10]);
                acc[11] = dot2_f16(__builtin_bit_cast(f16x2, hc.w), b, acc[11]);
                acc[12] = dot2_f16(__builtin_bit_cast(f16x2, hd.x), b, acc[12]);
                acc[13] = dot2_f16(__builtin_bit_cast(f16x2, hd.y), b, acc[13]);
                acc[14] = dot2_f16(__builtin_bit_cast(f16x2, hd.z), b, acc[14]);
            }
            // store fpk row (fp16, XOR-swizzled): byte = q*1920 + k*128 + 2c
            #pragma unroll
            for (int k = 0; k < NK; ++k) {
                uint32 woff = (uint32)(q*1920 + k*128 + 2*c);
                woff ^= ((woff >> 7) & 7u) << 4;
                const f16 hv = (f16)acc[k];
                *(u16*)((char*)fpkA + woff) = __builtin_bit_cast(u16, hv);
            }
        }
    }
    __syncthreads();

    // ---------------- Phase C: out[16 x 128] = fpkA . WB via MFMA f16 ----------------
    {
        const int l   = t & 63;
        const int w   = t >> 6;
        const int col = l & 15;      // = A row = query index
        const int kg  = l >> 4;
        const int nt0 = w * 2;
        f32x4 acc0 = {0.f,0.f,0.f,0.f};
        f32x4 acc1 = {0.f,0.f,0.f,0.f};
        const f16* b0p = wb + ((nt0  )*30)*512 + l*8;
        const f16* b1p = wb + ((nt0+1)*30)*512 + l*8;
        const uint32 abase = (uint32)(col*1920 + kg*16);
        #pragma unroll 6
        for (int ks = 0; ks < 30; ++ks) {
            uint32 aoff = abase + (uint32)(ks*64);
            aoff ^= ((aoff >> 7) & 7u) << 4;
            const f16x8 a  = *(const f16x8*)((const char*)fpkA + aoff);
            const f16x8 b0 = *(const f16x8*)(b0p + ks*512);
            const f16x8 b1 = *(const f16x8*)(b1p + ks*512);
            acc0 = __builtin_amdgcn_mfma_f32_16x16x32_f16(a, b0, acc0, 0, 0, 0);
            acc1 = __builtin_amdgcn_mfma_f32_16x16x32_f16(a, b1, acc1, 0, 0, 0);
        }
        const int rbase = kg * 4;    // C/D: row=(lane>>4)*4+reg, col=lane&15
        #pragma unroll
        for (int r = 0; r < 4; ++r) {
            out[(q0 + rbase + r)*COUT + nt0*16 + col]      = acc0[r];
            out[(q0 + rbase + r)*COUT + nt0*16 + 16 + col] = acc1[r];
        }
    }
}

extern "C" void kernel_launch(void* const* d_in, const int* in_sizes, int n_in,
                              void* d_out, int out_size, void* d_ws, size_t ws_size,
                              hipStream_t stream) {
    const float* q_pts = (const float*)d_in[0];
    const float* s_pts = (const float*)d_in[1];
    const float* x     = (const float*)d_in[2];
    const float* wts   = (const float*)d_in[3];
    const float* kp    = (const float*)d_in[4];
    const int*   nind  = (const int*)d_in[5];
    float* out = (float*)d_out;

    f16* wb = (f16*)d_ws;
    f16* xh = (f16*)((char*)d_ws + WB_BYTES);
    const int use_xh = (ws_size >= (size_t)WB_BYTES + XH_BYTES) ? 1 : 0;

    if (use_xh)
        hipLaunchKernelGGL(xh_pack, dim3(3125), dim3(256), 0, stream, x, xh);
    hipLaunchKernelGGL(wb_pack, dim3(240), dim3(64), 0, stream, wts, wb);
    hipLaunchKernelGGL(kpconv_fused, dim3(NQ/QT), dim3(256), 0, stream,
                       q_pts, s_pts, x, xh, wb, kp, nind, out, use_xh);
}

// Round 4
// 93.661 us; speedup vs baseline: 4.4564x; 1.8421x over previous
//
#include <hip/hip_runtime.h>

#define NQ     50000
#define MS     50000
#define NH     32
#define NK     15
#define CIN    64
#define COUT   128
#define QT     16
#define KC     (NK*CIN)          // 960
#define INV_EXT (1.0f/0.06f)

typedef unsigned int   uint32;
typedef unsigned short u16;
typedef _Float16 f16;
typedef _Float16 f16x4 __attribute__((ext_vector_type(4)));
typedef _Float16 f16x8 __attribute__((ext_vector_type(8)));
typedef float    f32x4 __attribute__((ext_vector_type(4)));

#define WB_BYTES (8*30*64*8*2)   // 245760: W in MFMA B-fragment order
#define XH_BYTES (MS*CIN*2)      // 6,400,000: x as fp16

// ---- x f32 -> fp16 ----
__global__ __launch_bounds__(256)
void xh_pack(const float* __restrict__ x, f16* __restrict__ xh) {
    const int i = (blockIdx.x * 256 + threadIdx.x) * 4;
    const float4 v = *(const float4*)&x[i];
    f16x4 o; o[0]=(f16)v.x; o[1]=(f16)v.y; o[2]=(f16)v.z; o[3]=(f16)v.w;
    *(f16x4*)&xh[i] = o;
}

// ---- W [960][128] f32 -> WB fp16 in MFMA B-fragment order ----
// WB[nt][ks][lane][e]: lane = kg*16+col holds W[ks*32+kg*8+e][nt*16+col]
__global__ __launch_bounds__(64)
void wb_pack(const float* __restrict__ w, f16* __restrict__ wb) {
    const int nt = blockIdx.x / 30;
    const int ks = blockIdx.x % 30;
    const int l  = threadIdx.x;
    const int col = l & 15, kg = l >> 4;
    f16x8 frag;
    #pragma unroll
    for (int e = 0; e < 8; ++e)
        frag[e] = (f16)w[(ks*32 + kg*8 + e)*COUT + nt*16 + col];
    *(f16x8*)&wb[((nt*30 + ks)*64 + l)*8] = frag;
}

// ---- fused KPConv: all three phases ----
__global__ __launch_bounds__(256, 3)
void kpconv_fused(const float* __restrict__ q_pts,
                  const float* __restrict__ s_pts,
                  const float* __restrict__ x,
                  const f16*  __restrict__ xh,
                  const f16*  __restrict__ wb,
                  const float* __restrict__ kp,
                  const int*   __restrict__ nind,
                  float* __restrict__ out,
                  int use_xh)
{
    __shared__ u16 fpkA[QT*KC];      // 30720 B, fp16 bits, XOR-swizzled; head reused as nb[]
    __shared__ u16 hfrag[QT*528];    // 16896 B: per q 1056 B; [q*528 + lane*8 + e] = A-frag of h
    __shared__ u16 inds[QT*NH];      // 1024 B

    float* nb = (float*)fpkA;        // nb[q*100 + j*3 + d] (stride 100 dwords spreads banks)

    const int t  = threadIdx.x;
    const int q0 = blockIdx.x * QT;

    // ---------------- stage: centered neighbor coords + clamped indices ----------------
    #pragma unroll
    for (int p = t; p < QT*NH; p += 256) {
        const int q = p >> 5, j = p & 31;
        const int ind = nind[(q0 + q)*NH + j];
        const bool valid = (ind < MS);
        inds[p] = (u16)(valid ? ind : 0);
        float sx, sy, sz;
        if (valid) { sx = s_pts[ind*3+0]; sy = s_pts[ind*3+1]; sz = s_pts[ind*3+2]; }
        else       { sx = 1e6f; sy = 1e6f; sz = 1e6f; }    // shadow -> h = 0
        nb[q*100 + j*3 + 0] = sx - q_pts[(q0+q)*3+0];
        nb[q*100 + j*3 + 1] = sy - q_pts[(q0+q)*3+1];
        nb[q*100 + j*3 + 2] = sz - q_pts[(q0+q)*3+2];
    }
    __syncthreads();

    // ---------------- Phase A: h -> LDS in MFMA A-frag order ----------------
    // A[k][j] per q: lane l&15 = row k, elems j = (l>>4)*8+e.
    // Thread (q,k) produces rows: write f16x8 at [q*528 + (jg*16+k)*8].
    {
        const int q = t >> 4, k = t & 15;
        u16* hq = &hfrag[q*528];
        if (k < NK) {
            const float kx = kp[k*3+0], ky = kp[k*3+1], kz = kp[k*3+2];
            const float* nbq = &nb[q*100];
            #pragma unroll
            for (int jg = 0; jg < 4; ++jg) {
                f16x8 hv;
                #pragma unroll
                for (int jj = 0; jj < 8; ++jj) {
                    const int j = jg*8 + jj;
                    const float dx = nbq[j*3+0] - kx;
                    const float dy = nbq[j*3+1] - ky;
                    const float dz = nbq[j*3+2] - kz;
                    float h = 1.0f - sqrtf(dx*dx + dy*dy + dz*dz) * INV_EXT;
                    h = (h > 0.0f) ? h : 0.0f;
                    hv[jj] = (f16)h;
                }
                *(f16x8*)&hq[(jg*16 + k)*8] = hv;
            }
        } else {                      // k == 15: zero pad row (D row 15 discarded anyway)
            const f16x8 z = {};
            #pragma unroll
            for (int jg = 0; jg < 4; ++jg)
                *(f16x8*)&hq[(jg*16 + 15)*8] = z;
        }
    }
    __syncthreads();    // h ready; nb region dead -> fpkA writable

    // ---------------- Phase B: fpk = h . xg via MFMA ----------------
    // wave w handles q = w*4 .. w*4+3; per q: 4 n-tiles of 16 channels.
    {
        const int l  = t & 63, w = t >> 6;
        const int lc = l & 15, lg = l >> 4;
        #pragma unroll
        for (int qi = 0; qi < 4; ++qi) {
            const int q = w*4 + qi;
            // 8 neighbor indices for this lane's j-slots (j = lg*8+e)
            const uint4 iv = *(const uint4*)&inds[q*NH + lg*8];
            uint32 roff[8];
            roff[0] = (iv.x & 0xffffu) * CIN; roff[1] = (iv.x >> 16) * CIN;
            roff[2] = (iv.y & 0xffffu) * CIN; roff[3] = (iv.y >> 16) * CIN;
            roff[4] = (iv.z & 0xffffu) * CIN; roff[5] = (iv.z >> 16) * CIN;
            roff[6] = (iv.w & 0xffffu) * CIN; roff[7] = (iv.w >> 16) * CIN;
            // A-frag of h (one ds_read_b128)
            const f16x8 a = *(const f16x8*)&hfrag[q*528 + l*8];
            f32x4 acc0 = {0,0,0,0}, acc1 = {0,0,0,0}, acc2 = {0,0,0,0}, acc3 = {0,0,0,0};
            #pragma unroll
            for (int ct = 0; ct < 4; ++ct) {
                const int cc = ct*16 + lc;
                f16x8 b;
                if (use_xh) {
                    #pragma unroll
                    for (int e = 0; e < 8; ++e) b[e] = xh[roff[e] + cc];
                } else {
                    #pragma unroll
                    for (int e = 0; e < 8; ++e) b[e] = (f16)x[roff[e] + cc];
                }
                if      (ct == 0) acc0 = __builtin_amdgcn_mfma_f32_16x16x32_f16(a, b, acc0, 0,0,0);
                else if (ct == 1) acc1 = __builtin_amdgcn_mfma_f32_16x16x32_f16(a, b, acc1, 0,0,0);
                else if (ct == 2) acc2 = __builtin_amdgcn_mfma_f32_16x16x32_f16(a, b, acc2, 0,0,0);
                else              acc3 = __builtin_amdgcn_mfma_f32_16x16x32_f16(a, b, acc3, 0,0,0);
            }
            // D (col=c=lc+ct*16, row=k=lg*4+r) -> fp16 -> swizzled fpkA
            #pragma unroll
            for (int ct = 0; ct < 4; ++ct) {
                const f32x4 acc = (ct==0)?acc0:(ct==1)?acc1:(ct==2)?acc2:acc3;
                #pragma unroll
                for (int r = 0; r < 4; ++r) {
                    const int k = lg*4 + r;
                    if (k < NK) {
                        uint32 woff = (uint32)(q*1920 + k*128 + (ct*16 + lc)*2);
                        woff ^= ((woff >> 7) & 7u) << 4;
                        const f16 hv = (f16)acc[r];
                        *(u16*)((char*)fpkA + woff) = __builtin_bit_cast(u16, hv);
                    }
                }
            }
        }
    }
    __syncthreads();

    // ---------------- Phase C: out[16 x 128] = fpkA . WB via MFMA ----------------
    {
        const int l   = t & 63;
        const int w   = t >> 6;
        const int col = l & 15;      // = A row = query index
        const int kg  = l >> 4;
        const int nt0 = w * 2;
        f32x4 acc0 = {0.f,0.f,0.f,0.f};
        f32x4 acc1 = {0.f,0.f,0.f,0.f};
        const f16* b0p = wb + ((nt0  )*30)*512 + l*8;
        const f16* b1p = wb + ((nt0+1)*30)*512 + l*8;
        const uint32 abase = (uint32)(col*1920 + kg*16);
        #pragma unroll 6
        for (int ks = 0; ks < 30; ++ks) {
            uint32 aoff = abase + (uint32)(ks*64);
            aoff ^= ((aoff >> 7) & 7u) << 4;
            const f16x8 a  = *(const f16x8*)((const char*)fpkA + aoff);
            const f16x8 b0 = *(const f16x8*)(b0p + ks*512);
            const f16x8 b1 = *(const f16x8*)(b1p + ks*512);
            acc0 = __builtin_amdgcn_mfma_f32_16x16x32_f16(a, b0, acc0, 0, 0, 0);
            acc1 = __builtin_amdgcn_mfma_f32_16x16x32_f16(a, b1, acc1, 0, 0, 0);
        }
        const int rbase = kg * 4;    // C/D: row=(lane>>4)*4+reg, col=lane&15
        #pragma unroll
        for (int r = 0; r < 4; ++r) {
            out[(q0 + rbase + r)*COUT + nt0*16 + col]      = acc0[r];
            out[(q0 + rbase + r)*COUT + nt0*16 + 16 + col] = acc1[r];
        }
    }
}

extern "C" void kernel_launch(void* const* d_in, const int* in_sizes, int n_in,
                              void* d_out, int out_size, void* d_ws, size_t ws_size,
                              hipStream_t stream) {
    const float* q_pts = (const float*)d_in[0];
    const float* s_pts = (const float*)d_in[1];
    const float* x     = (const float*)d_in[2];
    const float* wts   = (const float*)d_in[3];
    const float* kp    = (const float*)d_in[4];
    const int*   nind  = (const int*)d_in[5];
    float* out = (float*)d_out;

    f16* wb = (f16*)d_ws;
    f16* xh = (f16*)((char*)d_ws + WB_BYTES);
    const int use_xh = (ws_size >= (size_t)WB_BYTES + XH_BYTES) ? 1 : 0;

    if (use_xh)
        hipLaunchKernelGGL(xh_pack, dim3(3125), dim3(256), 0, stream, x, xh);
    hipLaunchKernelGGL(wb_pack, dim3(240), dim3(64), 0, stream, wts, wb);
    hipLaunchKernelGGL(kpconv_fused, dim3(NQ/QT), dim3(256), 0, stream,
                       q_pts, s_pts, x, xh, wb, kp, nind, out, use_xh);
}

// Round 5
// 77.533 us; speedup vs baseline: 5.3834x; 1.2080x over previous
//
#include <hip/hip_runtime.h>

#define NQ     50000
#define MS     50000
#define NH     32
#define NK     15
#define CIN    64
#define COUT   128
#define QT     16
#define INV_EXT (1.0f/0.06f)

typedef unsigned int   uint32;
typedef unsigned short u16;
typedef _Float16 f16;
typedef _Float16 f16x8 __attribute__((ext_vector_type(8)));
typedef float    f32x4 __attribute__((ext_vector_type(4)));

#define WB_BYTES  (8*32*64*8*2)   // 262144: W packed for K'=c*16+k enumeration (K=1024)
#define XPH_BYTES (MS*CIN*2)      // 6,400,000: x fp16, channel-permuted

#if __has_builtin(__builtin_amdgcn_sqrtf)
#define SQRTF __builtin_amdgcn_sqrtf
#else
#define SQRTF sqrtf
#endif

// dst = (A.lo16, B.lo16) / (A.hi16, B.hi16)
__device__ __forceinline__ uint32 permlo(uint32 A, uint32 B) {
#if __has_builtin(__builtin_amdgcn_perm)
    return __builtin_amdgcn_perm(A, B, 0x01000504u);
#else
    return (A & 0xffffu) | (B << 16);
#endif
}
__device__ __forceinline__ uint32 permhi(uint32 A, uint32 B) {
#if __has_builtin(__builtin_amdgcn_perm)
    return __builtin_amdgcn_perm(A, B, 0x03020706u);
#else
    return (A >> 16) | (B & 0xffff0000u);
#endif
}

// fpkAT swizzle: involution, XORs bits 4-6 with (q&7) and bit 4 with addr bit 7.
__device__ __forceinline__ uint32 swA(uint32 o) {
    return o ^ ((((o >> 11) & 7u) ^ ((o >> 7) & 1u)) << 4);
}

__device__ __forceinline__ u16 f16bits(float f) {
    return __builtin_bit_cast(u16, (f16)f);
}

// ---- x [M][64] f32 -> xph fp16, channel-permuted: xph[row][p] = x[row][(p&3)*16 + (p>>2)] ----
__global__ __launch_bounds__(256)
void xph_pack(const float* __restrict__ x, u16* __restrict__ xph) {
    const int tid = blockIdx.x * 256 + threadIdx.x;   // 800000 = 50000*16
    const int row = tid >> 4;
    const int lp  = tid & 15;
    const float v0 = x[row*CIN +  0 + lp];
    const float v1 = x[row*CIN + 16 + lp];
    const float v2 = x[row*CIN + 32 + lp];
    const float v3 = x[row*CIN + 48 + lp];
    uint2 d;
    d.x = (uint32)f16bits(v0) | ((uint32)f16bits(v1) << 16);
    d.y = (uint32)f16bits(v2) | ((uint32)f16bits(v3) << 16);
    *(uint2*)&xph[row*CIN + lp*4] = d;
}

// ---- W [15][64][128] f32 -> WB fp16 B-frags for K' = c*16 + k (k==15 -> 0) ----
// WB[nt][ks][lane][e]: lane l holds W at K' = ks*32 + (l>>4)*8 + e, n = nt*16 + (l&15)
__global__ __launch_bounds__(64)
void wb_pack(const float* __restrict__ w, u16* __restrict__ wb) {
    const int nt = blockIdx.x >> 5;   // 0..7
    const int ks = blockIdx.x & 31;   // 0..31
    const int l  = threadIdx.x;
    u16 frag[8];
    #pragma unroll
    for (int e = 0; e < 8; ++e) {
        const int Kp = ks*32 + (l >> 4)*8 + e;
        const int c  = Kp >> 4;
        const int k  = Kp & 15;
        const float val = (k < NK) ? w[(k*CIN + c)*COUT + nt*16 + (l & 15)] : 0.0f;
        frag[e] = f16bits(val);
    }
    *(f16x8*)&wb[((nt*32 + ks)*64 + l)*8] = *(f16x8*)frag;
}

// ---- fused KPConv ----
__global__ __launch_bounds__(256, 3)
void kpconv_fused(const float* __restrict__ q_pts,
                  const float* __restrict__ s_pts,
                  const u16*  __restrict__ xph,
                  const u16*  __restrict__ wb,
                  const float* __restrict__ kp,
                  const int*   __restrict__ nind,
                  float* __restrict__ out)
{
    __shared__ u16 fpkAT[QT*1024];   // 32768 B: [q][c][k16] fp16, swA-swizzled; head reused as nb[]
    __shared__ u16 hfrag[QT*528];    // 16896 B: [q][lane][8] = MFMA A-frag of h (K=32, j natural)
    __shared__ u16 inds[QT*NH];      // 1024 B

    float* nb = (float*)fpkAT;       // nb[q*100 + j*3 + d]

    const int t  = threadIdx.x;
    const int q0 = blockIdx.x * QT;

    // ---------------- stage: centered neighbor coords + clamped indices ----------------
    #pragma unroll
    for (int p = t; p < QT*NH; p += 256) {
        const int q = p >> 5, j = p & 31;
        const int ind = nind[(q0 + q)*NH + j];
        const bool valid = (ind < MS);
        inds[p] = (u16)(valid ? ind : 0);
        float sx, sy, sz;
        if (valid) { sx = s_pts[ind*3+0]; sy = s_pts[ind*3+1]; sz = s_pts[ind*3+2]; }
        else       { sx = 1e6f; sy = 1e6f; sz = 1e6f; }    // shadow -> h = 0
        nb[q*100 + j*3 + 0] = sx - q_pts[(q0+q)*3+0];
        nb[q*100 + j*3 + 1] = sy - q_pts[(q0+q)*3+1];
        nb[q*100 + j*3 + 2] = sz - q_pts[(q0+q)*3+2];
    }
    __syncthreads();

    // ---------------- Phase A: h -> LDS A-frags (row k=l&15, elems j=(l>>4)*8+e) ----------------
    {
        const int q = t >> 4, k = t & 15;
        u16* hq = &hfrag[q*528];
        if (k < NK) {
            const float kx = kp[k*3+0], ky = kp[k*3+1], kz = kp[k*3+2];
            const float* nbq = &nb[q*100];
            #pragma unroll
            for (int jg = 0; jg < 4; ++jg) {
                u16 hv[8];
                #pragma unroll
                for (int jj = 0; jj < 8; ++jj) {
                    const int j = jg*8 + jj;
                    const float dx = nbq[j*3+0] - kx;
                    const float dy = nbq[j*3+1] - ky;
                    const float dz = nbq[j*3+2] - kz;
                    float h = 1.0f - SQRTF(dx*dx + dy*dy + dz*dz) * INV_EXT;
                    h = (h > 0.0f) ? h : 0.0f;
                    hv[jj] = f16bits(h);
                }
                *(f16x8*)&hq[(jg*16 + k)*8] = *(f16x8*)hv;
            }
        } else {                      // k == 15: zero pad row -> Phase B D row 15 == 0
            const f16x8 z = {};
            #pragma unroll
            for (int jg = 0; jg < 4; ++jg)
                *(f16x8*)&hq[(jg*16 + 15)*8] = z;
        }
    }
    __syncthreads();    // h ready; nb region dead -> fpkAT writable

    // ---------------- Phase B: fpk = h . xg via MFMA, wide permuted gathers ----------------
    {
        const int l  = t & 63, wv = t >> 6;
        const int lc = l & 15, lg = l >> 4;
        #pragma unroll
        for (int qi = 0; qi < 4; ++qi) {
            const int q = wv*4 + qi;
            const uint4 iv = *(const uint4*)&inds[q*NH + lg*8];
            uint32 r[8];
            r[0] = iv.x & 0xffffu; r[1] = iv.x >> 16;
            r[2] = iv.y & 0xffffu; r[3] = iv.y >> 16;
            r[4] = iv.z & 0xffffu; r[5] = iv.z >> 16;
            r[6] = iv.w & 0xffffu; r[7] = iv.w >> 16;
            // one 8-B load per j-slot: channels {lc, 16+lc, 32+lc, 48+lc} of row j=lg*8+e
            uint2 v0 = *(const uint2*)(xph + r[0]*CIN + lc*4);
            uint2 v1 = *(const uint2*)(xph + r[1]*CIN + lc*4);
            uint2 v2 = *(const uint2*)(xph + r[2]*CIN + lc*4);
            uint2 v3 = *(const uint2*)(xph + r[3]*CIN + lc*4);
            uint2 v4 = *(const uint2*)(xph + r[4]*CIN + lc*4);
            uint2 v5 = *(const uint2*)(xph + r[5]*CIN + lc*4);
            uint2 v6 = *(const uint2*)(xph + r[6]*CIN + lc*4);
            uint2 v7 = *(const uint2*)(xph + r[7]*CIN + lc*4);
            const f16x8 a = *(const f16x8*)&hfrag[q*528 + l*8];
            f32x4 acc0 = {0,0,0,0}, acc1 = {0,0,0,0}, acc2 = {0,0,0,0}, acc3 = {0,0,0,0};
            #pragma unroll
            for (int ct = 0; ct < 4; ++ct) {
                const uint32 A0 = (ct & 2) ? v0.y : v0.x, B0 = (ct & 2) ? v1.y : v1.x;
                const uint32 A1 = (ct & 2) ? v2.y : v2.x, B1 = (ct & 2) ? v3.y : v3.x;
                const uint32 A2 = (ct & 2) ? v4.y : v4.x, B2 = (ct & 2) ? v5.y : v5.x;
                const uint32 A3 = (ct & 2) ? v6.y : v6.x, B3 = (ct & 2) ? v7.y : v7.x;
                uint4 bd;
                if (ct & 1) {
                    bd.x = permhi(A0, B0); bd.y = permhi(A1, B1);
                    bd.z = permhi(A2, B2); bd.w = permhi(A3, B3);
                } else {
                    bd.x = permlo(A0, B0); bd.y = permlo(A1, B1);
                    bd.z = permlo(A2, B2); bd.w = permlo(A3, B3);
                }
                const f16x8 b = __builtin_bit_cast(f16x8, bd);
                if      (ct == 0) acc0 = __builtin_amdgcn_mfma_f32_16x16x32_f16(a, b, acc0, 0,0,0);
                else if (ct == 1) acc1 = __builtin_amdgcn_mfma_f32_16x16x32_f16(a, b, acc1, 0,0,0);
                else if (ct == 2) acc2 = __builtin_amdgcn_mfma_f32_16x16x32_f16(a, b, acc2, 0,0,0);
                else              acc3 = __builtin_amdgcn_mfma_f32_16x16x32_f16(a, b, acc3, 0,0,0);
            }
            // writeback: D (row k=lg*4+r, col c=ct*16+lc) -> fpkAT[q][c][k], one b64 per ct
            #pragma unroll
            for (int ct = 0; ct < 4; ++ct) {
                const f32x4 av = (ct==0)?acc0:(ct==1)?acc1:(ct==2)?acc2:acc3;
                uint2 dv;
                dv.x = (uint32)f16bits(av[0]) | ((uint32)f16bits(av[1]) << 16);
                dv.y = (uint32)f16bits(av[2]) | ((uint32)f16bits(av[3]) << 16);
                const uint32 o = swA((uint32)(q*2048 + (ct*16 + lc)*32 + lg*8));
                *(uint2*)((char*)fpkAT + o) = dv;
            }
        }
    }
    __syncthreads();

    // ---------------- Phase C: out[16 x 128] = fpkAT . WB via MFMA (K=1024) ----------------
    {
        const int l   = t & 63;
        const int w   = t >> 6;
        const int col = l & 15;      // A row = query
        const int kg  = l >> 4;
        const int nt0 = w * 2;
        f32x4 acc0 = {0.f,0.f,0.f,0.f};
        f32x4 acc1 = {0.f,0.f,0.f,0.f};
        const u16* b0p = wb + (nt0*32)*512 + l*8;
        const u16* b1p = b0p + 32*512;
        const uint32 abase = (uint32)(col*2048 + kg*16);
        #pragma unroll 8
        for (int ks = 0; ks < 32; ++ks) {
            const uint32 aoff = swA(abase + (uint32)(ks*64));
            const f16x8 a  = *(const f16x8*)((const char*)fpkAT + aoff);
            const f16x8 b0 = *(const f16x8*)(b0p + ks*512);
            const f16x8 b1 = *(const f16x8*)(b1p + ks*512);
            acc0 = __builtin_amdgcn_mfma_f32_16x16x32_f16(a, b0, acc0, 0, 0, 0);
            acc1 = __builtin_amdgcn_mfma_f32_16x16x32_f16(a, b1, acc1, 0, 0, 0);
        }
        const int rbase = kg * 4;    // D: row=(lane>>4)*4+reg (query), col=lane&15 (channel)
        #pragma unroll
        for (int r = 0; r < 4; ++r) {
            out[(q0 + rbase + r)*COUT + nt0*16 + col]      = acc0[r];
            out[(q0 + rbase + r)*COUT + nt0*16 + 16 + col] = acc1[r];
        }
    }
}

extern "C" void kernel_launch(void* const* d_in, const int* in_sizes, int n_in,
                              void* d_out, int out_size, void* d_ws, size_t ws_size,
                              hipStream_t stream) {
    const float* q_pts = (const float*)d_in[0];
    const float* s_pts = (const float*)d_in[1];
    const float* x     = (const float*)d_in[2];
    const float* wts   = (const float*)d_in[3];
    const float* kp    = (const float*)d_in[4];
    const int*   nind  = (const int*)d_in[5];
    float* out = (float*)d_out;

    u16* wbp = (u16*)d_ws;
    u16* xph = (u16*)((char*)d_ws + WB_BYTES);

    hipLaunchKernelGGL(xph_pack, dim3(3125), dim3(256), 0, stream, x, xph);
    hipLaunchKernelGGL(wb_pack,  dim3(256),  dim3(64),  0, stream, wts, wbp);
    hipLaunchKernelGGL(kpconv_fused, dim3(NQ/QT), dim3(256), 0, stream,
                       q_pts, s_pts, xph, wbp, kp, nind, out);
}

// Round 6
// 74.182 us; speedup vs baseline: 5.6266x; 1.0452x over previous
//
#include <hip/hip_runtime.h>

#define NQ     50000
#define MS     50000
#define NH     32
#define NK     15
#define CIN    64
#define COUT   128
#define QT     16
#define INV_EXT (1.0f/0.06f)

typedef unsigned int   uint32;
typedef unsigned short u16;
typedef _Float16 f16;
typedef _Float16 f16x8 __attribute__((ext_vector_type(8)));
typedef float    f32x4 __attribute__((ext_vector_type(4)));

#define WB_BYTES  (8*32*64*8*2)   // 262144: W packed for K'=c*16+k enumeration (K=1024)
#define XPH_BYTES (MS*CIN*2)      // 6,400,000: x fp16, channel-permuted

// dst = (A.lo16, B.lo16) / (A.hi16, B.hi16)
__device__ __forceinline__ uint32 permlo(uint32 A, uint32 B) {
#if __has_builtin(__builtin_amdgcn_perm)
    return __builtin_amdgcn_perm(A, B, 0x01000504u);
#else
    return (A & 0xffffu) | (B << 16);
#endif
}
__device__ __forceinline__ uint32 permhi(uint32 A, uint32 B) {
#if __has_builtin(__builtin_amdgcn_perm)
    return __builtin_amdgcn_perm(A, B, 0x03020706u);
#else
    return (A >> 16) | (B & 0xffff0000u);
#endif
}

// fpkAT swizzle: involution, XORs bits 4-6 with (q&7) and bit 4 with addr bit 7.
__device__ __forceinline__ uint32 swA(uint32 o) {
    return o ^ ((((o >> 11) & 7u) ^ ((o >> 7) & 1u)) << 4);
}

__device__ __forceinline__ u16 f16bits(float f) {
    return __builtin_bit_cast(u16, (f16)f);
}

// ---- x [M][64] f32 -> xph fp16, channel-permuted: xph[row][p] = x[row][(p&3)*16 + (p>>2)] ----
__global__ __launch_bounds__(256)
void xph_pack(const float* __restrict__ x, u16* __restrict__ xph) {
    const int tid = blockIdx.x * 256 + threadIdx.x;   // 800000 = 50000*16
    const int row = tid >> 4;
    const int lp  = tid & 15;
    const float v0 = x[row*CIN +  0 + lp];
    const float v1 = x[row*CIN + 16 + lp];
    const float v2 = x[row*CIN + 32 + lp];
    const float v3 = x[row*CIN + 48 + lp];
    uint2 d;
    d.x = (uint32)f16bits(v0) | ((uint32)f16bits(v1) << 16);
    d.y = (uint32)f16bits(v2) | ((uint32)f16bits(v3) << 16);
    *(uint2*)&xph[row*CIN + lp*4] = d;
}

// ---- W [15][64][128] f32 -> WB fp16 B-frags for K' = c*16 + k (k==15 -> 0) ----
// WB[nt][ks][lane][e]: lane l holds W at K' = ks*32 + (l>>4)*8 + e, n = nt*16 + (l&15)
__global__ __launch_bounds__(64)
void wb_pack(const float* __restrict__ w, u16* __restrict__ wb) {
    const int nt = blockIdx.x >> 5;   // 0..7
    const int ks = blockIdx.x & 31;   // 0..31
    const int l  = threadIdx.x;
    u16 frag[8];
    #pragma unroll
    for (int e = 0; e < 8; ++e) {
        const int Kp = ks*32 + (l >> 4)*8 + e;
        const int c  = Kp >> 4;
        const int k  = Kp & 15;
        const float val = (k < NK) ? w[(k*CIN + c)*COUT + nt*16 + (l & 15)] : 0.0f;
        frag[e] = f16bits(val);
    }
    *(f16x8*)&wb[((nt*32 + ks)*64 + l)*8] = *(f16x8*)frag;
}

// ---- fused KPConv: h computed in-register inside Phase B (no hfrag LDS) ----
__global__ __launch_bounds__(256, 4)
void kpconv_fused(const float* __restrict__ q_pts,
                  const float* __restrict__ s_pts,
                  const u16*  __restrict__ xph,
                  const u16*  __restrict__ wb,
                  const float* __restrict__ kp,
                  const int*   __restrict__ nind,
                  float* __restrict__ out)
{
    __shared__ u16   fpkAT[QT*1024];   // 32768 B: [q][c][k16] fp16, swA-swizzled
    __shared__ float nb[QT*100];       // 6400 B: centered neighbor coords [q*100 + j*3 + d]
    __shared__ u16   inds[QT*NH];      // 1024 B
                                       // total 40192 B -> 4 blocks/CU

    const int t  = threadIdx.x;
    const int q0 = blockIdx.x * QT;

    // ---------------- stage: centered neighbor coords + clamped indices ----------------
    #pragma unroll
    for (int p = t; p < QT*NH; p += 256) {
        const int q = p >> 5, j = p & 31;
        const int ind = nind[(q0 + q)*NH + j];
        const bool valid = (ind < MS);
        inds[p] = (u16)(valid ? ind : 0);
        float sx, sy, sz;
        if (valid) { sx = s_pts[ind*3+0]; sy = s_pts[ind*3+1]; sz = s_pts[ind*3+2]; }
        else       { sx = 1e6f; sy = 1e6f; sz = 1e6f; }    // shadow -> h = 0
        nb[q*100 + j*3 + 0] = sx - q_pts[(q0+q)*3+0];
        nb[q*100 + j*3 + 1] = sy - q_pts[(q0+q)*3+1];
        nb[q*100 + j*3 + 2] = sz - q_pts[(q0+q)*3+2];
    }
    __syncthreads();

    // ---------------- Phase B (A fused): fpk = h . xg via MFMA ----------------
    // A-frag per lane: row k = lc (15 -> clamped dup, dead via WB zeros), j = lg*8+e.
    {
        const int l  = t & 63, wv = t >> 6;
        const int lc = l & 15, lg = l >> 4;
        const int kc = (lc < NK) ? lc : (NK - 1);
        const float kx = kp[kc*3+0], ky = kp[kc*3+1], kz = kp[kc*3+2];
        #pragma unroll
        for (int qi = 0; qi < 4; ++qi) {
            const int q = wv*4 + qi;
            // ---- issue gathers first (latency hides under h-compute) ----
            const uint4 iv = *(const uint4*)&inds[q*NH + lg*8];
            uint32 r[8];
            r[0] = iv.x & 0xffffu; r[1] = iv.x >> 16;
            r[2] = iv.y & 0xffffu; r[3] = iv.y >> 16;
            r[4] = iv.z & 0xffffu; r[5] = iv.z >> 16;
            r[6] = iv.w & 0xffffu; r[7] = iv.w >> 16;
            uint2 v0 = *(const uint2*)(xph + r[0]*CIN + lc*4);
            uint2 v1 = *(const uint2*)(xph + r[1]*CIN + lc*4);
            uint2 v2 = *(const uint2*)(xph + r[2]*CIN + lc*4);
            uint2 v3 = *(const uint2*)(xph + r[3]*CIN + lc*4);
            uint2 v4 = *(const uint2*)(xph + r[4]*CIN + lc*4);
            uint2 v5 = *(const uint2*)(xph + r[5]*CIN + lc*4);
            uint2 v6 = *(const uint2*)(xph + r[6]*CIN + lc*4);
            uint2 v7 = *(const uint2*)(xph + r[7]*CIN + lc*4);
            // ---- h for this lane's A-frag (broadcast nb reads within 16-lane groups) ----
            const float* nbq = &nb[q*100 + lg*24];
            const float4 r0 = *(const float4*)(nbq +  0);
            const float4 r1 = *(const float4*)(nbq +  4);
            const float4 r2 = *(const float4*)(nbq +  8);
            const float4 r3 = *(const float4*)(nbq + 12);
            const float4 r4 = *(const float4*)(nbq + 16);
            const float4 r5 = *(const float4*)(nbq + 20);
            float jx[8], jy[8], jz[8];
            jx[0]=r0.x; jy[0]=r0.y; jz[0]=r0.z;
            jx[1]=r0.w; jy[1]=r1.x; jz[1]=r1.y;
            jx[2]=r1.z; jy[2]=r1.w; jz[2]=r2.x;
            jx[3]=r2.y; jy[3]=r2.z; jz[3]=r2.w;
            jx[4]=r3.x; jy[4]=r3.y; jz[4]=r3.z;
            jx[5]=r3.w; jy[5]=r4.x; jz[5]=r4.y;
            jx[6]=r4.z; jy[6]=r4.w; jz[6]=r5.x;
            jx[7]=r5.y; jy[7]=r5.z; jz[7]=r5.w;
            u16 hb[8];
            #pragma unroll
            for (int e = 0; e < 8; ++e) {
                const float dx = jx[e] - kx;
                const float dy = jy[e] - ky;
                const float dz = jz[e] - kz;
                float hh = 1.0f - sqrtf(dx*dx + dy*dy + dz*dz) * INV_EXT;
                hh = (hh > 0.0f) ? hh : 0.0f;
                hb[e] = f16bits(hh);
            }
            const f16x8 a = *(const f16x8*)hb;
            // ---- 4 MFMA over channel tiles ----
            f32x4 acc0 = {0,0,0,0}, acc1 = {0,0,0,0}, acc2 = {0,0,0,0}, acc3 = {0,0,0,0};
            #pragma unroll
            for (int ct = 0; ct < 4; ++ct) {
                const uint32 A0 = (ct & 2) ? v0.y : v0.x, B0 = (ct & 2) ? v1.y : v1.x;
                const uint32 A1 = (ct & 2) ? v2.y : v2.x, B1 = (ct & 2) ? v3.y : v3.x;
                const uint32 A2 = (ct & 2) ? v4.y : v4.x, B2 = (ct & 2) ? v5.y : v5.x;
                const uint32 A3 = (ct & 2) ? v6.y : v6.x, B3 = (ct & 2) ? v7.y : v7.x;
                uint4 bd;
                if (ct & 1) {
                    bd.x = permhi(A0, B0); bd.y = permhi(A1, B1);
                    bd.z = permhi(A2, B2); bd.w = permhi(A3, B3);
                } else {
                    bd.x = permlo(A0, B0); bd.y = permlo(A1, B1);
                    bd.z = permlo(A2, B2); bd.w = permlo(A3, B3);
                }
                const f16x8 b = __builtin_bit_cast(f16x8, bd);
                if      (ct == 0) acc0 = __builtin_amdgcn_mfma_f32_16x16x32_f16(a, b, acc0, 0,0,0);
                else if (ct == 1) acc1 = __builtin_amdgcn_mfma_f32_16x16x32_f16(a, b, acc1, 0,0,0);
                else if (ct == 2) acc2 = __builtin_amdgcn_mfma_f32_16x16x32_f16(a, b, acc2, 0,0,0);
                else              acc3 = __builtin_amdgcn_mfma_f32_16x16x32_f16(a, b, acc3, 0,0,0);
            }
            // writeback: D (row k=lg*4+r, col c=ct*16+lc) -> fpkAT[q][c][k], one b64 per ct
            #pragma unroll
            for (int ct = 0; ct < 4; ++ct) {
                const f32x4 av = (ct==0)?acc0:(ct==1)?acc1:(ct==2)?acc2:acc3;
                uint2 dv;
                dv.x = (uint32)f16bits(av[0]) | ((uint32)f16bits(av[1]) << 16);
                dv.y = (uint32)f16bits(av[2]) | ((uint32)f16bits(av[3]) << 16);
                const uint32 o = swA((uint32)(q*2048 + (ct*16 + lc)*32 + lg*8));
                *(uint2*)((char*)fpkAT + o) = dv;
            }
        }
    }
    __syncthreads();

    // ---------------- Phase C: out[16 x 128] = fpkAT . WB via MFMA (K=1024) ----------------
    {
        const int l   = t & 63;
        const int w   = t >> 6;
        const int col = l & 15;      // A row = query
        const int kg  = l >> 4;
        const int nt0 = w * 2;
        f32x4 acc0 = {0.f,0.f,0.f,0.f};
        f32x4 acc1 = {0.f,0.f,0.f,0.f};
        const u16* b0p = wb + (nt0*32)*512 + l*8;
        const u16* b1p = b0p + 32*512;
        const uint32 abase = (uint32)(col*2048 + kg*16);
        #pragma unroll 8
        for (int ks = 0; ks < 32; ++ks) {
            const uint32 aoff = swA(abase + (uint32)(ks*64));
            const f16x8 a  = *(const f16x8*)((const char*)fpkAT + aoff);
            const f16x8 b0 = *(const f16x8*)(b0p + ks*512);
            const f16x8 b1 = *(const f16x8*)(b1p + ks*512);
            acc0 = __builtin_amdgcn_mfma_f32_16x16x32_f16(a, b0, acc0, 0, 0, 0);
            acc1 = __builtin_amdgcn_mfma_f32_16x16x32_f16(a, b1, acc1, 0, 0, 0);
        }
        const int rbase = kg * 4;    // D: row=(lane>>4)*4+reg (query), col=lane&15 (channel)
        #pragma unroll
        for (int r = 0; r < 4; ++r) {
            out[(q0 + rbase + r)*COUT + nt0*16 + col]      = acc0[r];
            out[(q0 + rbase + r)*COUT + nt0*16 + 16 + col] = acc1[r];
        }
    }
}

extern "C" void kernel_launch(void* const* d_in, const int* in_sizes, int n_in,
                              void* d_out, int out_size, void* d_ws, size_t ws_size,
                              hipStream_t stream) {
    const float* q_pts = (const float*)d_in[0];
    const float* s_pts = (const float*)d_in[1];
    const float* x     = (const float*)d_in[2];
    const float* wts   = (const float*)d_in[3];
    const float* kp    = (const float*)d_in[4];
    const int*   nind  = (const int*)d_in[5];
    float* out = (float*)d_out;

    u16* wbp = (u16*)d_ws;
    u16* xph = (u16*)((char*)d_ws + WB_BYTES);

    hipLaunchKernelGGL(xph_pack, dim3(3125), dim3(256), 0, stream, x, xph);
    hipLaunchKernelGGL(wb_pack,  dim3(256),  dim3(64),  0, stream, wts, wbp);
    hipLaunchKernelGGL(kpconv_fused, dim3(NQ/QT), dim3(256), 0, stream,
                       q_pts, s_pts, xph, wbp, kp, nind, out);
}

// Round 8
// 67.245 us; speedup vs baseline: 6.2070x; 1.1032x over previous
//
#include <hip/hip_runtime.h>

#define NQ     50000
#define MS     50000
#define NH     32
#define NK     15
#define CIN    64
#define COUT   128
#define QT     16
#define INV_EXT (1.0f/0.06f)

typedef unsigned int   uint32;
typedef unsigned short u16;
typedef _Float16 f16;
typedef _Float16 f16x8 __attribute__((ext_vector_type(8)));
typedef float    f32x4 __attribute__((ext_vector_type(4)));

#define WB_BYTES  (8*32*64*8*2)   // 262144: W packed for K'=c*16+k enumeration (K=1024)
#define XPH_BYTES (MS*CIN*2)      // 6,400,000: x fp16, channel-permuted

#if __has_builtin(__builtin_amdgcn_sqrtf)
#define SQRTF __builtin_amdgcn_sqrtf
#else
#define SQRTF sqrtf
#endif

// dst = (A.lo16, B.lo16) / (A.hi16, B.hi16)
__device__ __forceinline__ uint32 permlo(uint32 A, uint32 B) {
#if __has_builtin(__builtin_amdgcn_perm)
    return __builtin_amdgcn_perm(A, B, 0x01000504u);
#else
    return (A & 0xffffu) | (B << 16);
#endif
}
__device__ __forceinline__ uint32 permhi(uint32 A, uint32 B) {
#if __has_builtin(__builtin_amdgcn_perm)
    return __builtin_amdgcn_perm(A, B, 0x03020706u);
#else
    return (A >> 16) | (B & 0xffff0000u);
#endif
}

__device__ __forceinline__ u16 f16bits(float f) {
    return __builtin_bit_cast(u16, (f16)f);
}

// packed f32x2 -> f16x2 bits (one v_cvt_pkrtz_f16_f32)
__device__ __forceinline__ uint32 pk2(float a, float b) {
#if __has_builtin(__builtin_amdgcn_cvt_pkrtz)
    return __builtin_bit_cast(uint32, __builtin_amdgcn_cvt_pkrtz(a, b));
#else
    return (uint32)f16bits(a) | ((uint32)f16bits(b) << 16);
#endif
}

// fpkAT swizzle: involution, XORs bits 4-6 with (q&7) and bit 4 with addr bit 7.
__device__ __forceinline__ uint32 swA(uint32 o) {
    return o ^ ((((o >> 11) & 7u) ^ ((o >> 7) & 1u)) << 4);
}

// ---- merged pack: blocks [0,3125): xph; blocks [3125,3189): wb ----
// xph[row][p] = fp16 x[row][(p&3)*16 + (p>>2)]
// WB[nt][ks][lane][e]: lane l holds W at K' = ks*32 + (l>>4)*8 + e, n = nt*16 + (l&15)
__global__ __launch_bounds__(256)
void pack_all(const float* __restrict__ x, u16* __restrict__ xph,
              const float* __restrict__ w, u16* __restrict__ wb) {
    const int bid = blockIdx.x;
    if (bid < 3125) {
        const int tid = bid * 256 + threadIdx.x;   // 800000 = 50000*16
        const int row = tid >> 4;
        const int lp  = tid & 15;
        const float v0 = x[row*CIN +  0 + lp];
        const float v1 = x[row*CIN + 16 + lp];
        const float v2 = x[row*CIN + 32 + lp];
        const float v3 = x[row*CIN + 48 + lp];
        uint2 d;
        d.x = pk2(v0, v1);
        d.y = pk2(v2, v3);
        *(uint2*)&xph[row*CIN + lp*4] = d;
    } else {
        const int u  = (bid - 3125) * 4 + (threadIdx.x >> 6);  // 0..255 (nt,ks) units
        const int nt = u >> 5;            // 0..7
        const int ks = u & 31;            // 0..31
        const int l  = threadIdx.x & 63;
        u16 frag[8];
        #pragma unroll
        for (int e = 0; e < 8; ++e) {
            const int Kp = ks*32 + (l >> 4)*8 + e;
            const int c  = Kp >> 4;
            const int k  = Kp & 15;
            const float val = (k < NK) ? w[(k*CIN + c)*COUT + nt*16 + (l & 15)] : 0.0f;
            frag[e] = f16bits(val);
        }
        *(f16x8*)&wb[((nt*32 + ks)*64 + l)*8] = *(f16x8*)frag;
    }
}

// ---- fused KPConv: h in-register, all gathers prefetched ----
__global__ __launch_bounds__(256, 4)
void kpconv_fused(const float* __restrict__ q_pts,
                  const float* __restrict__ s_pts,
                  const u16*  __restrict__ xph,
                  const u16*  __restrict__ wb,
                  const float* __restrict__ kp,
                  const int*   __restrict__ nind,
                  float* __restrict__ out)
{
    __shared__ u16   fpkAT[QT*1024];   // 32768 B: [q][c][k16] fp16, swA-swizzled
    __shared__ float nb[QT*100];       // 6400 B: centered neighbor coords [q*100 + j*3 + d]
    __shared__ u16   inds[QT*NH];      // 1024 B
                                       // total 40192 B -> 4 blocks/CU

    const int t  = threadIdx.x;
    const int q0 = blockIdx.x * QT;

    // ---------------- stage: centered neighbor coords + clamped indices ----------------
    #pragma unroll
    for (int p = t; p < QT*NH; p += 256) {
        const int q = p >> 5, j = p & 31;
        const int ind = nind[(q0 + q)*NH + j];
        const bool valid = (ind < MS);
        inds[p] = (u16)(valid ? ind : 0);
        float sx, sy, sz;
        if (valid) { sx = s_pts[ind*3+0]; sy = s_pts[ind*3+1]; sz = s_pts[ind*3+2]; }
        else       { sx = 1e6f; sy = 1e6f; sz = 1e6f; }    // shadow -> h = 0
        nb[q*100 + j*3 + 0] = sx - q_pts[(q0+q)*3+0];
        nb[q*100 + j*3 + 1] = sy - q_pts[(q0+q)*3+1];
        nb[q*100 + j*3 + 2] = sz - q_pts[(q0+q)*3+2];
    }
    __syncthreads();

    // ---------------- Phase B (A fused): fpk = h . xg via MFMA ----------------
    // A-frag per lane: row k = lc (15 -> clamped dup, dead via WB zeros), j = lg*8+e.
    {
        const int l  = t & 63, wv = t >> 6;
        const int lc = l & 15, lg = l >> 4;
        const int kc = (lc < NK) ? lc : (NK - 1);
        const float kx = kp[kc*3+0], ky = kp[kc*3+1], kz = kp[kc*3+2];

        // ---- prefetch ALL 32 gathers (4 qi x 8 j-slots), fully static ----
        uint2 v[4][8];
        #pragma unroll
        for (int qi = 0; qi < 4; ++qi) {
            const int q = wv*4 + qi;
            const uint4 iv = *(const uint4*)&inds[q*NH + lg*8];
            uint32 r[8];
            r[0] = iv.x & 0xffffu; r[1] = iv.x >> 16;
            r[2] = iv.y & 0xffffu; r[3] = iv.y >> 16;
            r[4] = iv.z & 0xffffu; r[5] = iv.z >> 16;
            r[6] = iv.w & 0xffffu; r[7] = iv.w >> 16;
            #pragma unroll
            for (int e = 0; e < 8; ++e)
                v[qi][e] = *(const uint2*)(xph + r[e]*CIN + lc*4);
        }

        #pragma unroll
        for (int qi = 0; qi < 4; ++qi) {
            const int q = wv*4 + qi;
            // ---- h for this lane's A-frag (broadcast nb reads within 16-lane groups) ----
            const float* nbq = &nb[q*100 + lg*24];
            const float4 r0 = *(const float4*)(nbq +  0);
            const float4 r1 = *(const float4*)(nbq +  4);
            const float4 r2 = *(const float4*)(nbq +  8);
            const float4 r3 = *(const float4*)(nbq + 12);
            const float4 r4 = *(const float4*)(nbq + 16);
            const float4 r5 = *(const float4*)(nbq + 20);
            float jx[8], jy[8], jz[8];
            jx[0]=r0.x; jy[0]=r0.y; jz[0]=r0.z;
            jx[1]=r0.w; jy[1]=r1.x; jz[1]=r1.y;
            jx[2]=r1.z; jy[2]=r1.w; jz[2]=r2.x;
            jx[3]=r2.y; jy[3]=r2.z; jz[3]=r2.w;
            jx[4]=r3.x; jy[4]=r3.y; jz[4]=r3.z;
            jx[5]=r3.w; jy[5]=r4.x; jz[5]=r4.y;
            jx[6]=r4.z; jy[6]=r4.w; jz[6]=r5.x;
            jx[7]=r5.y; jy[7]=r5.z; jz[7]=r5.w;
            float hh[8];
            #pragma unroll
            for (int e = 0; e < 8; ++e) {
                const float dx = jx[e] - kx;
                const float dy = jy[e] - ky;
                const float dz = jz[e] - kz;
                float h = 1.0f - SQRTF(dx*dx + dy*dy + dz*dz) * INV_EXT;
                hh[e] = (h > 0.0f) ? h : 0.0f;
            }
            uint32 ab[4];
            ab[0] = pk2(hh[0], hh[1]); ab[1] = pk2(hh[2], hh[3]);
            ab[2] = pk2(hh[4], hh[5]); ab[3] = pk2(hh[6], hh[7]);
            const f16x8 a = __builtin_bit_cast(f16x8, *(uint4*)ab);
            // ---- 4 MFMA over channel tiles ----
            f32x4 acc0 = {0,0,0,0}, acc1 = {0,0,0,0}, acc2 = {0,0,0,0}, acc3 = {0,0,0,0};
            #pragma unroll
            for (int ct = 0; ct < 4; ++ct) {
                const uint32 A0 = (ct & 2) ? v[qi][0].y : v[qi][0].x, B0 = (ct & 2) ? v[qi][1].y : v[qi][1].x;
                const uint32 A1 = (ct & 2) ? v[qi][2].y : v[qi][2].x, B1 = (ct & 2) ? v[qi][3].y : v[qi][3].x;
                const uint32 A2 = (ct & 2) ? v[qi][4].y : v[qi][4].x, B2 = (ct & 2) ? v[qi][5].y : v[qi][5].x;
                const uint32 A3 = (ct & 2) ? v[qi][6].y : v[qi][6].x, B3 = (ct & 2) ? v[qi][7].y : v[qi][7].x;
                uint4 bd;
                if (ct & 1) {
                    bd.x = permhi(A0, B0); bd.y = permhi(A1, B1);
                    bd.z = permhi(A2, B2); bd.w = permhi(A3, B3);
                } else {
                    bd.x = permlo(A0, B0); bd.y = permlo(A1, B1);
                    bd.z = permlo(A2, B2); bd.w = permlo(A3, B3);
                }
                const f16x8 b = __builtin_bit_cast(f16x8, bd);
                if      (ct == 0) acc0 = __builtin_amdgcn_mfma_f32_16x16x32_f16(a, b, acc0, 0,0,0);
                else if (ct == 1) acc1 = __builtin_amdgcn_mfma_f32_16x16x32_f16(a, b, acc1, 0,0,0);
                else if (ct == 2) acc2 = __builtin_amdgcn_mfma_f32_16x16x32_f16(a, b, acc2, 0,0,0);
                else              acc3 = __builtin_amdgcn_mfma_f32_16x16x32_f16(a, b, acc3, 0,0,0);
            }
            // writeback: D (row k=lg*4+r, col c=ct*16+lc) -> fpkAT[q][c][k], one b64 per ct
            #pragma unroll
            for (int ct = 0; ct < 4; ++ct) {
                const f32x4 av = (ct==0)?acc0:(ct==1)?acc1:(ct==2)?acc2:acc3;
                uint2 dv;
                dv.x = pk2(av[0], av[1]);
                dv.y = pk2(av[2], av[3]);
                const uint32 o = swA((uint32)(q*2048 + (ct*16 + lc)*32 + lg*8));
                *(uint2*)((char*)fpkAT + o) = dv;
            }
        }
    }
    __syncthreads();

    // ---------------- Phase C: out[16 x 128] = fpkAT . WB via MFMA (K=1024) ----------------
    {
        const int l   = t & 63;
        const int w   = t >> 6;
        const int col = l & 15;      // A row = query
        const int kg  = l >> 4;
        const int nt0 = w * 2;
        f32x4 acc0 = {0.f,0.f,0.f,0.f};
        f32x4 acc1 = {0.f,0.f,0.f,0.f};
        const u16* b0p = wb + (nt0*32)*512 + l*8;
        const u16* b1p = b0p + 32*512;
        const uint32 abase = (uint32)(col*2048 + kg*16);
        #pragma unroll 8
        for (int ks = 0; ks < 32; ++ks) {
            const uint32 aoff = swA(abase + (uint32)(ks*64));
            const f16x8 a  = *(const f16x8*)((const char*)fpkAT + aoff);
            const f16x8 b0 = *(const f16x8*)(b0p + ks*512);
            const f16x8 b1 = *(const f16x8*)(b1p + ks*512);
            acc0 = __builtin_amdgcn_mfma_f32_16x16x32_f16(a, b0, acc0, 0, 0, 0);
            acc1 = __builtin_amdgcn_mfma_f32_16x16x32_f16(a, b1, acc1, 0, 0, 0);
        }
        const int rbase = kg * 4;    // D: row=(lane>>4)*4+reg (query), col=lane&15 (channel)
        #pragma unroll
        for (int r = 0; r < 4; ++r) {
            out[(q0 + rbase + r)*COUT + nt0*16 + col]      = acc0[r];
            out[(q0 + rbase + r)*COUT + nt0*16 + 16 + col] = acc1[r];
        }
    }
}

extern "C" void kernel_launch(void* const* d_in, const int* in_sizes, int n_in,
                              void* d_out, int out_size, void* d_ws, size_t ws_size,
                              hipStream_t stream) {
    const float* q_pts = (const float*)d_in[0];
    const float* s_pts = (const float*)d_in[1];
    const float* x     = (const float*)d_in[2];
    const float* wts   = (const float*)d_in[3];
    const float* kp    = (const float*)d_in[4];
    const int*   nind  = (const int*)d_in[5];
    float* out = (float*)d_out;

    u16* wbp = (u16*)d_ws;
    u16* xph = (u16*)((char*)d_ws + WB_BYTES);

    hipLaunchKernelGGL(pack_all, dim3(3125 + 64), dim3(256), 0, stream, x, xph, wts, wbp);
    hipLaunchKernelGGL(kpconv_fused, dim3(NQ/QT), dim3(256), 0, stream,
                       q_pts, s_pts, xph, wbp, kp, nind, out);
}

// Round 9
// 64.560 us; speedup vs baseline: 6.4652x; 1.0416x over previous
//
#include <hip/hip_runtime.h>

#define NQ     50000
#define MS     50000
#define NH     32
#define NK     15
#define CIN    64
#define COUT   128
#define QT     32
#define INV_EXT (1.0f/0.06f)

typedef unsigned int   uint32;
typedef unsigned short u16;
typedef _Float16 f16;
typedef _Float16 f16x8 __attribute__((ext_vector_type(8)));
typedef float    f32x4 __attribute__((ext_vector_type(4)));

#define WB_BYTES  (8*32*64*8*2)   // 262144: W packed for K'=c*16+k enumeration (K=1024)
#define XPH_BYTES (MS*CIN*2)      // 6,400,000: x fp16, channel-permuted

#if __has_builtin(__builtin_amdgcn_sqrtf)
#define SQRTF __builtin_amdgcn_sqrtf
#else
#define SQRTF sqrtf
#endif

// dst = (A.lo16, B.lo16) / (A.hi16, B.hi16)
__device__ __forceinline__ uint32 permlo(uint32 A, uint32 B) {
#if __has_builtin(__builtin_amdgcn_perm)
    return __builtin_amdgcn_perm(A, B, 0x01000504u);
#else
    return (A & 0xffffu) | (B << 16);
#endif
}
__device__ __forceinline__ uint32 permhi(uint32 A, uint32 B) {
#if __has_builtin(__builtin_amdgcn_perm)
    return __builtin_amdgcn_perm(A, B, 0x03020706u);
#else
    return (A >> 16) | (B & 0xffff0000u);
#endif
}

__device__ __forceinline__ u16 f16bits(float f) {
    return __builtin_bit_cast(u16, (f16)f);
}

// packed f32x2 -> f16x2 bits (one v_cvt_pkrtz_f16_f32)
__device__ __forceinline__ uint32 pk2(float a, float b) {
#if __has_builtin(__builtin_amdgcn_cvt_pkrtz)
    return __builtin_bit_cast(uint32, __builtin_amdgcn_cvt_pkrtz(a, b));
#else
    return (uint32)f16bits(a) | ((uint32)f16bits(b) << 16);
#endif
}

// fpkAT swizzle: involution, XORs bits 4-6 with (q&7) and bit 4 with addr bit 7.
__device__ __forceinline__ uint32 swA(uint32 o) {
    return o ^ ((((o >> 11) & 7u) ^ ((o >> 7) & 1u)) << 4);
}

// ---- merged pack: blocks [0,3125): xph; blocks [3125,3189): wb ----
// xph[row][p] = fp16 x[row][(p&3)*16 + (p>>2)]
// WB[nt][ks][lane][e]: lane l holds W at K' = ks*32 + (l>>4)*8 + e, n = nt*16 + (l&15)
__global__ __launch_bounds__(256)
void pack_all(const float* __restrict__ x, u16* __restrict__ xph,
              const float* __restrict__ w, u16* __restrict__ wb) {
    const int bid = blockIdx.x;
    if (bid < 3125) {
        const int tid = bid * 256 + threadIdx.x;   // 800000 = 50000*16
        const int row = tid >> 4;
        const int lp  = tid & 15;
        const float v0 = x[row*CIN +  0 + lp];
        const float v1 = x[row*CIN + 16 + lp];
        const float v2 = x[row*CIN + 32 + lp];
        const float v3 = x[row*CIN + 48 + lp];
        uint2 d;
        d.x = pk2(v0, v1);
        d.y = pk2(v2, v3);
        *(uint2*)&xph[row*CIN + lp*4] = d;
    } else {
        const int u  = (bid - 3125) * 4 + (threadIdx.x >> 6);  // 0..255 (nt,ks) units
        const int nt = u >> 5;            // 0..7
        const int ks = u & 31;            // 0..31
        const int l  = threadIdx.x & 63;
        u16 frag[8];
        #pragma unroll
        for (int e = 0; e < 8; ++e) {
            const int Kp = ks*32 + (l >> 4)*8 + e;
            const int c  = Kp >> 4;
            const int k  = Kp & 15;
            const float val = (k < NK) ? w[(k*CIN + c)*COUT + nt*16 + (l & 15)] : 0.0f;
            frag[e] = f16bits(val);
        }
        *(f16x8*)&wb[((nt*32 + ks)*64 + l)*8] = *(f16x8*)frag;
    }
}

// ---- fused KPConv: QT=32, 8 waves; Phase C: wave=nt, both A-tiles ----
__global__ __launch_bounds__(512, 4)
void kpconv_fused(const float* __restrict__ q_pts,
                  const float* __restrict__ s_pts,
                  const u16*  __restrict__ xph,
                  const u16*  __restrict__ wb,
                  const float* __restrict__ kp,
                  const int*   __restrict__ nind,
                  float* __restrict__ out)
{
    __shared__ u16   fpkAT[QT*1024];   // 65536 B: [q][c][k16] fp16, swA-swizzled
    __shared__ float nb[QT*100];       // 12800 B: centered neighbor coords
    __shared__ u16   inds[QT*NH];      // 2048 B
                                       // total 80384 B -> 2 blocks/CU

    const int t  = threadIdx.x;
    const int q0 = blockIdx.x * QT;

    // ---------------- stage: centered neighbor coords + clamped indices ----------------
    #pragma unroll
    for (int p = t; p < QT*NH; p += 512) {
        const int q = p >> 5, j = p & 31;
        const int qg = q0 + q;
        const int qc = (qg < NQ) ? qg : (NQ - 1);    // clamp for padded tail
        const int ind = nind[qc*NH + j];
        const bool valid = (ind < MS);
        inds[p] = (u16)(valid ? ind : 0);
        float sx, sy, sz;
        if (valid) { sx = s_pts[ind*3+0]; sy = s_pts[ind*3+1]; sz = s_pts[ind*3+2]; }
        else       { sx = 1e6f; sy = 1e6f; sz = 1e6f; }    // shadow -> h = 0
        nb[q*100 + j*3 + 0] = sx - q_pts[qc*3+0];
        nb[q*100 + j*3 + 1] = sy - q_pts[qc*3+1];
        nb[q*100 + j*3 + 2] = sz - q_pts[qc*3+2];
    }
    __syncthreads();

    // ---------------- Phase B (A fused): fpk = h . xg via MFMA ----------------
    // A-frag per lane: row k = lc (15 -> clamped dup, dead via WB zeros), j = lg*8+e.
    {
        const int l  = t & 63, wv = t >> 6;          // wv 0..7
        const int lc = l & 15, lg = l >> 4;
        const int kc = (lc < NK) ? lc : (NK - 1);
        const float kx = kp[kc*3+0], ky = kp[kc*3+1], kz = kp[kc*3+2];

        // ---- prefetch ALL 32 gathers (4 qi x 8 j-slots), fully static ----
        uint2 v[4][8];
        #pragma unroll
        for (int qi = 0; qi < 4; ++qi) {
            const int q = wv*4 + qi;
            const uint4 iv = *(const uint4*)&inds[q*NH + lg*8];
            uint32 r[8];
            r[0] = iv.x & 0xffffu; r[1] = iv.x >> 16;
            r[2] = iv.y & 0xffffu; r[3] = iv.y >> 16;
            r[4] = iv.z & 0xffffu; r[5] = iv.z >> 16;
            r[6] = iv.w & 0xffffu; r[7] = iv.w >> 16;
            #pragma unroll
            for (int e = 0; e < 8; ++e)
                v[qi][e] = *(const uint2*)(xph + r[e]*CIN + lc*4);
        }

        #pragma unroll
        for (int qi = 0; qi < 4; ++qi) {
            const int q = wv*4 + qi;
            // ---- h for this lane's A-frag (broadcast nb reads within 16-lane groups) ----
            const float* nbq = &nb[q*100 + lg*24];
            const float4 r0 = *(const float4*)(nbq +  0);
            const float4 r1 = *(const float4*)(nbq +  4);
            const float4 r2 = *(const float4*)(nbq +  8);
            const float4 r3 = *(const float4*)(nbq + 12);
            const float4 r4 = *(const float4*)(nbq + 16);
            const float4 r5 = *(const float4*)(nbq + 20);
            float jx[8], jy[8], jz[8];
            jx[0]=r0.x; jy[0]=r0.y; jz[0]=r0.z;
            jx[1]=r0.w; jy[1]=r1.x; jz[1]=r1.y;
            jx[2]=r1.z; jy[2]=r1.w; jz[2]=r2.x;
            jx[3]=r2.y; jy[3]=r2.z; jz[3]=r2.w;
            jx[4]=r3.x; jy[4]=r3.y; jz[4]=r3.z;
            jx[5]=r3.w; jy[5]=r4.x; jz[5]=r4.y;
            jx[6]=r4.z; jy[6]=r4.w; jz[6]=r5.x;
            jx[7]=r5.y; jy[7]=r5.z; jz[7]=r5.w;
            float hh[8];
            #pragma unroll
            for (int e = 0; e < 8; ++e) {
                const float dx = jx[e] - kx;
                const float dy = jy[e] - ky;
                const float dz = jz[e] - kz;
                float h = 1.0f - SQRTF(dx*dx + dy*dy + dz*dz) * INV_EXT;
                hh[e] = (h > 0.0f) ? h : 0.0f;
            }
            uint32 ab[4];
            ab[0] = pk2(hh[0], hh[1]); ab[1] = pk2(hh[2], hh[3]);
            ab[2] = pk2(hh[4], hh[5]); ab[3] = pk2(hh[6], hh[7]);
            const f16x8 a = __builtin_bit_cast(f16x8, *(uint4*)ab);
            // ---- 4 MFMA over channel tiles ----
            f32x4 acc0 = {0,0,0,0}, acc1 = {0,0,0,0}, acc2 = {0,0,0,0}, acc3 = {0,0,0,0};
            #pragma unroll
            for (int ct = 0; ct < 4; ++ct) {
                const uint32 A0 = (ct & 2) ? v[qi][0].y : v[qi][0].x, B0 = (ct & 2) ? v[qi][1].y : v[qi][1].x;
                const uint32 A1 = (ct & 2) ? v[qi][2].y : v[qi][2].x, B1 = (ct & 2) ? v[qi][3].y : v[qi][3].x;
                const uint32 A2 = (ct & 2) ? v[qi][4].y : v[qi][4].x, B2 = (ct & 2) ? v[qi][5].y : v[qi][5].x;
                const uint32 A3 = (ct & 2) ? v[qi][6].y : v[qi][6].x, B3 = (ct & 2) ? v[qi][7].y : v[qi][7].x;
                uint4 bd;
                if (ct & 1) {
                    bd.x = permhi(A0, B0); bd.y = permhi(A1, B1);
                    bd.z = permhi(A2, B2); bd.w = permhi(A3, B3);
                } else {
                    bd.x = permlo(A0, B0); bd.y = permlo(A1, B1);
                    bd.z = permlo(A2, B2); bd.w = permlo(A3, B3);
                }
                const f16x8 b = __builtin_bit_cast(f16x8, bd);
                if      (ct == 0) acc0 = __builtin_amdgcn_mfma_f32_16x16x32_f16(a, b, acc0, 0,0,0);
                else if (ct == 1) acc1 = __builtin_amdgcn_mfma_f32_16x16x32_f16(a, b, acc1, 0,0,0);
                else if (ct == 2) acc2 = __builtin_amdgcn_mfma_f32_16x16x32_f16(a, b, acc2, 0,0,0);
                else              acc3 = __builtin_amdgcn_mfma_f32_16x16x32_f16(a, b, acc3, 0,0,0);
            }
            // writeback: D (row k=lg*4+r, col c=ct*16+lc) -> fpkAT[q][c][k], one b64 per ct
            #pragma unroll
            for (int ct = 0; ct < 4; ++ct) {
                const f32x4 av = (ct==0)?acc0:(ct==1)?acc1:(ct==2)?acc2:acc3;
                uint2 dv;
                dv.x = pk2(av[0], av[1]);
                dv.y = pk2(av[2], av[3]);
                const uint32 o = swA((uint32)(q*2048 + (ct*16 + lc)*32 + lg*8));
                *(uint2*)((char*)fpkAT + o) = dv;
            }
        }
    }

    // ---- Phase C B-frag prefetch (independent of fpkAT; barrier drain lands them free) ----
    const int l   = t & 63;
    const int nt  = t >> 6;          // wave = one n-tile, both A-tiles
    const u16* bp = wb + (nt*32)*512 + l*8;
    uint4 pb0 = *(const uint4*)(bp + 0*512);
    uint4 pb1 = *(const uint4*)(bp + 1*512);
    uint4 pb2 = *(const uint4*)(bp + 2*512);
    uint4 pb3 = *(const uint4*)(bp + 3*512);

    __syncthreads();

    // ---------------- Phase C: out[32 x 128] = fpkAT . WB via MFMA (K=1024) ----------------
    {
        const int col = l & 15;      // A row = query (within A-tile)
        const int kg  = l >> 4;
        f32x4 acc0 = {0.f,0.f,0.f,0.f};   // queries q0..q0+15
        f32x4 acc1 = {0.f,0.f,0.f,0.f};   // queries q0+16..q0+31
        const uint32 abase0 = (uint32)(col*2048 + kg*16);
        const uint32 abase1 = abase0 + 16*2048;
        #pragma unroll 8
        for (int ks = 0; ks < 32; ++ks) {
            const uint32 aoff0 = swA(abase0 + (uint32)(ks*64));
            const uint32 aoff1 = swA(abase1 + (uint32)(ks*64));
            const f16x8 a0 = *(const f16x8*)((const char*)fpkAT + aoff0);
            const f16x8 a1 = *(const f16x8*)((const char*)fpkAT + aoff1);
            uint4 bd;
            if      (ks == 0) bd = pb0;
            else if (ks == 1) bd = pb1;
            else if (ks == 2) bd = pb2;
            else if (ks == 3) bd = pb3;
            else              bd = *(const uint4*)(bp + ks*512);
            const f16x8 b = __builtin_bit_cast(f16x8, bd);
            acc0 = __builtin_amdgcn_mfma_f32_16x16x32_f16(a0, b, acc0, 0, 0, 0);
            acc1 = __builtin_amdgcn_mfma_f32_16x16x32_f16(a1, b, acc1, 0, 0, 0);
        }
        const int rbase = kg * 4;    // D: row=(lane>>4)*4+reg (query), col=lane&15 (channel)
        #pragma unroll
        for (int r = 0; r < 4; ++r) {
            const int row0 = q0 + rbase + r;
            const int row1 = row0 + 16;
            if (row0 < NQ) out[row0*COUT + nt*16 + col] = acc0[r];
            if (row1 < NQ) out[row1*COUT + nt*16 + col] = acc1[r];
        }
    }
}

extern "C" void kernel_launch(void* const* d_in, const int* in_sizes, int n_in,
                              void* d_out, int out_size, void* d_ws, size_t ws_size,
                              hipStream_t stream) {
    const float* q_pts = (const float*)d_in[0];
    const float* s_pts = (const float*)d_in[1];
    const float* x     = (const float*)d_in[2];
    const float* wts   = (const float*)d_in[3];
    const float* kp    = (const float*)d_in[4];
    const int*   nind  = (const int*)d_in[5];
    float* out = (float*)d_out;

    u16* wbp = (u16*)d_ws;
    u16* xph = (u16*)((char*)d_ws + WB_BYTES);

    hipLaunchKernelGGL(pack_all, dim3(3125 + 64), dim3(256), 0, stream, x, xph, wts, wbp);
    hipLaunchKernelGGL(kpconv_fused, dim3((NQ + QT - 1) / QT), dim3(512), 0, stream,
                       q_pts, s_pts, xph, wbp, kp, nind, out);
}